// Round 5
// baseline (308.427 us; speedup 1.0000x reference)
//
#include <hip/hip_runtime.h>
#include <hip/hip_fp16.h>
#include <stdint.h>

// Problem constants
#define Bb 8
#define Tt 4096
#define Cc 512
#define Hh 512
#define Mm (Bb*Tt)      // 32768
#define Nn (3*Hh)       // 1536
#define Kk (2*Cc)       // 1024
#define NC 256          // chunks per batch for the scan
#define LC (Tt/NC)      // 16 steps per chunk
#define XBS (Tt*Cc + Cc) // per-batch padded x stride (elems) = 2097664
#define BK 64

typedef _Float16 half8 __attribute__((ext_vector_type(8)));
typedef _Float16 half4 __attribute__((ext_vector_type(4)));
typedef float  floatx4 __attribute__((ext_vector_type(4)));
typedef float  floatx2 __attribute__((ext_vector_type(2)));

typedef const __attribute__((address_space(1))) uint32_t* gptr_t;
typedef __attribute__((address_space(3))) uint32_t* lptr_t;

__device__ __forceinline__ void g2lds16(const void* g, void* l) {
    __builtin_amdgcn_global_load_lds((gptr_t)g, (lptr_t)l, 16, 0, 0);
}

__device__ __forceinline__ float fsigmoid(float x) {
    return 1.0f / (1.0f + __expf(-x));
}
__device__ __forceinline__ float ftanh(float x) {
    return 2.0f / (1.0f + __expf(-2.0f * x)) - 1.0f;
}

// ---- x fp32 -> fp16 with 512-elem zero pad at front of each batch ----
__global__ __launch_bounds__(256) void cvt_x(const float* __restrict__ x,
                                             _Float16* __restrict__ xh) {
    long i4 = ((long)blockIdx.x * 256 + threadIdx.x) * 4;   // [0, XBS)
    int b = blockIdx.y;
    if (i4 >= XBS) return;
    half4 v;
    if (i4 >= Cc) {
        floatx4 xx = *(const floatx4*)&x[(long)b * (Tt*Cc) + i4 - Cc];
        v[0] = (_Float16)xx[0]; v[1] = (_Float16)xx[1];
        v[2] = (_Float16)xx[2]; v[3] = (_Float16)xx[3];
    } else {
        v[0] = v[1] = v[2] = v[3] = (_Float16)0.0f;
    }
    *(half4*)&xh[(long)b * XBS + i4] = v;
}

// ---- build Bt[n][kk] via LDS-tiled transpose (both sides coalesced) ----
__global__ __launch_bounds__(256) void cvt_w(const float* __restrict__ zk,
                                             const float* __restrict__ fk,
                                             const float* __restrict__ ok,
                                             _Float16* __restrict__ bt) {
    __shared__ float tile[64][65];
    const int c0 = (blockIdx.x & 7) * 64;
    const int h0 = (blockIdx.x >> 3) * 64;
    const int which = blockIdx.y >> 1;
    const int kw    = blockIdx.y & 1;
    const float* src = (which == 0) ? zk : ((which == 1) ? fk : ok);
    src += kw * (Cc * Hh);
    const int tr  = threadIdx.x >> 4;
    const int tc4 = (threadIdx.x & 15) * 4;
#pragma unroll
    for (int i = 0; i < 4; ++i) {
        int c = tr + i * 16;
        floatx4 v = *(const floatx4*)&src[(long)(c0 + c) * Hh + h0 + tc4];
        tile[c][tc4 + 0] = v[0]; tile[c][tc4 + 1] = v[1];
        tile[c][tc4 + 2] = v[2]; tile[c][tc4 + 3] = v[3];
    }
    __syncthreads();
#pragma unroll
    for (int i = 0; i < 4; ++i) {
        int h = tr + i * 16;
        half4 o;
#pragma unroll
        for (int j = 0; j < 4; ++j) o[j] = (_Float16)tile[tc4 + j][h];
        *(half4*)&bt[((long)(which * 512 + h0 + h) << 10) + kw * 512 + c0 + tc4] = o;
    }
}

// ---- MFMA fp16 GEMM with coalesced+swizzled LDS staging (R3, unchanged) ----
__global__ __launch_bounds__(256, 3) void gemm_qrnn(const _Float16* __restrict__ xh,
                                                    const _Float16* __restrict__ bt,
                                                    const float* __restrict__ zb,
                                                    const float* __restrict__ fb,
                                                    const float* __restrict__ ob,
                                                    _Float16* __restrict__ yh) {
    __shared__ _Float16 lA[128 * BK];
    __shared__ _Float16 lB[128 * BK];

    const int tid  = threadIdx.x;
    const int lane = tid & 63;
    const int w    = tid >> 6;
    const int m0   = blockIdx.x * 128;
    const int n0   = blockIdx.y * 128;
    const int wm   = (w & 1) * 64;
    const int wn   = (w >> 1) * 64;
    const int q    = lane >> 4;
    const int l15  = lane & 15;

    const int rl = lane >> 3;
    const int j  = lane & 7;
    const int jx = (j ^ rl) * 8;

    const _Float16* asrc[4];
    const _Float16* bsrc[4];
    _Float16* adst[4];
    _Float16* bdst[4];
#pragma unroll
    for (int i = 0; i < 4; ++i) {
        int r0 = w * 32 + i * 8;
        int rgA = m0 + r0 + rl;
        asrc[i] = xh + (((long)(rgA + (rgA >> 12))) << 9) + jx;
        int rgB = n0 + r0 + rl;
        bsrc[i] = bt + (((long)rgB) << 10) + jx;
        adst[i] = &lA[r0 * BK];
        bdst[i] = &lB[r0 * BK];
    }

    int aaddr[4], baddr[4];
    const int psw = (q ^ (l15 & 7)) * 8;
#pragma unroll
    for (int i = 0; i < 4; ++i) {
        aaddr[i] = (wm + i * 16 + l15) * BK + psw;
        baddr[i] = (wn + i * 16 + l15) * BK + psw;
    }

    floatx4 acc[4][4] = {};

    for (int kt = 0; kt < Kk / BK; ++kt) {
        const int kb = kt * BK;
#pragma unroll
        for (int i = 0; i < 4; ++i) g2lds16(asrc[i] + kb, adst[i]);
#pragma unroll
        for (int i = 0; i < 4; ++i) g2lds16(bsrc[i] + kb, bdst[i]);
        __syncthreads();

        half8 a0[4], a1[4], b0[4], b1[4];
#pragma unroll
        for (int i = 0; i < 4; ++i) {
            a0[i] = *(const half8*)&lA[aaddr[i]];
            a1[i] = *(const half8*)&lA[aaddr[i] ^ 32];
            b0[i] = *(const half8*)&lB[baddr[i]];
            b1[i] = *(const half8*)&lB[baddr[i] ^ 32];
        }
#pragma unroll
        for (int mi = 0; mi < 4; ++mi)
#pragma unroll
            for (int ni = 0; ni < 4; ++ni)
                acc[mi][ni] = __builtin_amdgcn_mfma_f32_16x16x32_f16(
                    a0[mi], b0[ni], acc[mi][ni], 0, 0, 0);
#pragma unroll
        for (int mi = 0; mi < 4; ++mi)
#pragma unroll
            for (int ni = 0; ni < 4; ++ni)
                acc[mi][ni] = __builtin_amdgcn_mfma_f32_16x16x32_f16(
                    a1[mi], b1[ni], acc[mi][ni], 0, 0, 0);
        __syncthreads();
    }

    const int gate = n0 >> 9;
    const float* bias = (gate == 0) ? zb : ((gate == 1) ? fb : ob);
    float bv[4];
#pragma unroll
    for (int ni = 0; ni < 4; ++ni)
        bv[ni] = bias[(n0 & 511) + wn + ni * 16 + l15];

#pragma unroll
    for (int mi = 0; mi < 4; ++mi) {
#pragma unroll
        for (int ni = 0; ni < 4; ++ni) {
#pragma unroll
            for (int r = 0; r < 4; ++r) {
                int m = m0 + wm + mi * 16 + q * 4 + r;
                int n = n0 + wn + ni * 16 + l15;
                float v = acc[mi][ni][r] + bv[ni];
                float a = (gate == 0) ? ftanh(v) : fsigmoid(v);
                yh[(long)m * Nn + n] = (_Float16)a;
            }
        }
    }
}

// ---- scan pass 1: per-chunk local scan (h_in = 0), 4 chunks per block ----
// wave w handles chunk (blockIdx.x&63)*4+w of batch blockIdx.x>>6.
// Fully unrolled LC=16 -> compiler hoists loads; pf/he packed as float2.
__global__ __launch_bounds__(256) void scan_partial(const _Float16* __restrict__ yh,
                                                    floatx2* __restrict__ pfhe) {
    int wv   = threadIdx.x >> 6;
    int lane = threadIdx.x & 63;
    int b    = blockIdx.x >> 6;
    int c    = (blockIdx.x & 63) * 4 + wv;
    long base = ((long)(b * Tt + c * LC)) * Nn + lane * 8;
    float hl[8] = {0,0,0,0,0,0,0,0};
    float p[8]  = {1,1,1,1,1,1,1,1};
#pragma unroll
    for (int t = 0; t < LC; ++t) {
        half8 z8 = *(const half8*)&yh[base + (long)t * Nn];
        half8 f8 = *(const half8*)&yh[base + (long)t * Nn + 512];
#pragma unroll
        for (int jj = 0; jj < 8; ++jj) {
            float f = (float)f8[jj];
            hl[jj] = f * hl[jj] + (1.0f - f) * (float)z8[jj];
            p[jj] *= f;
        }
    }
    long o = ((long)(b * NC + c)) * Hh + lane * 8;
#pragma unroll
    for (int jj = 0; jj < 8; ++jj) {
        floatx2 v; v[0] = p[jj]; v[1] = hl[jj];
        pfhe[o + jj] = v;
    }
}

// ---- scan pass 2: sequential combine over chunks -> h_in per chunk ----
__global__ __launch_bounds__(64) void scan_combine(const floatx2* __restrict__ pfhe,
                                                   float* __restrict__ hin) {
    int idx = blockIdx.x * 64 + threadIdx.x; // b*512 + h, 4096 total (64 blocks)
    int b = idx >> 9;
    int h = idx & 511;
    float hcur = 0.0f;
#pragma unroll 8
    for (int c = 0; c < NC; ++c) {
        long o = ((long)(b * NC + c)) * Hh + h;
        hin[o] = hcur;
        floatx2 v = pfhe[o];
        hcur = v[0] * hcur + v[1];
    }
}

// ---- scan pass 3: local scan with true h_in, apply o-gate, write out ----
__global__ __launch_bounds__(256) void scan_final(const _Float16* __restrict__ yh,
                                                  const float* __restrict__ hin,
                                                  float* __restrict__ out) {
    int wv   = threadIdx.x >> 6;
    int lane = threadIdx.x & 63;
    int b    = blockIdx.x >> 6;
    int c    = (blockIdx.x & 63) * 4 + wv;
    long base  = ((long)(b * Tt + c * LC)) * Nn + lane * 8;
    long obase = ((long)(b * Tt + c * LC)) * Hh + lane * 8;
    long hb    = ((long)(b * NC + c)) * Hh + lane * 8;
    float h[8];
#pragma unroll
    for (int jj = 0; jj < 8; ++jj) h[jj] = hin[hb + jj];
#pragma unroll
    for (int t = 0; t < LC; ++t) {
        half8 z8 = *(const half8*)&yh[base + (long)t * Nn];
        half8 f8 = *(const half8*)&yh[base + (long)t * Nn + 512];
        half8 o8 = *(const half8*)&yh[base + (long)t * Nn + 1024];
        floatx4 o0, o1;
#pragma unroll
        for (int jj = 0; jj < 8; ++jj) {
            float f = (float)f8[jj];
            h[jj] = f * h[jj] + (1.0f - f) * (float)z8[jj];
            float r = h[jj] * (float)o8[jj];
            if (jj < 4) o0[jj] = r; else o1[jj - 4] = r;
        }
        __builtin_nontemporal_store(o0, (floatx4*)&out[obase + (long)t * Hh]);
        __builtin_nontemporal_store(o1, (floatx4*)&out[obase + (long)t * Hh + 4]);
    }
}

extern "C" void kernel_launch(void* const* d_in, const int* in_sizes, int n_in,
                              void* d_out, int out_size, void* d_ws, size_t ws_size,
                              hipStream_t stream) {
    const float* x  = (const float*)d_in[0];
    const float* zk = (const float*)d_in[1];
    const float* zbias = (const float*)d_in[2];
    const float* fk = (const float*)d_in[3];
    const float* fbias = (const float*)d_in[4];
    const float* ok = (const float*)d_in[5];
    const float* obias = (const float*)d_in[6];
    float* out = (float*)d_out;

    // Workspace layout: xh 33.5 MB | bt 3 MB | yh 100.6 MB (total 137.4 MB)
    // pfhe (8 MB) + hin (4 MB) overlay xh (dead after gemm; stream-ordered).
    char* ws = (char*)d_ws;
    _Float16* xh = (_Float16*)ws;
    _Float16* bt = (_Float16*)(ws + 33562624);
    _Float16* yh = (_Float16*)(ws + 36708352);
    floatx2*  pfhe = (floatx2*)(ws);             // 8*256*512*8 = 8,388,608
    float*    hin  = (float*)(ws + 8388608);     // 4,194,304 (ends 12.6 MB)

    cvt_x<<<dim3((XBS/4 + 255) / 256, Bb), 256, 0, stream>>>(x, xh);
    cvt_w<<<dim3(64, 6), 256, 0, stream>>>(zk, fk, ok, bt);
    gemm_qrnn<<<dim3(Mm / 128, Nn / 128), 256, 0, stream>>>(xh, bt, zbias, fbias, obias, yh);
    scan_partial<<<dim3(Bb * NC / 4), 256, 0, stream>>>(yh, pfhe);
    scan_combine<<<dim3(64), 64, 0, stream>>>(pfhe, hin);
    scan_final<<<dim3(Bb * NC / 4), 256, 0, stream>>>(yh, hin, out);
}